// Round 1
// baseline (763.414 us; speedup 1.0000x reference)
//
#include <hip/hip_runtime.h>

#define D_TOK 768
#define NS 8192
#define NQ 8192
#define NL 6
#define KDIM 1536

typedef __attribute__((ext_vector_type(4))) float f32x4;
typedef __attribute__((ext_vector_type(8))) short bf16x8;
typedef unsigned int u32;
typedef unsigned short u16;

__device__ __forceinline__ u16 f2bf(float f) {
    u32 u = __float_as_uint(f);
    u32 r = (u + 0x7FFFu + ((u >> 16) & 1u)) >> 16;  // RNE
    return (u16)r;
}

// order-preserving float->uint encoding (monotonic under unsigned compare)
__device__ __forceinline__ u32 encf(float f) {
    u32 u = __float_as_uint(f);
    return (u & 0x80000000u) ? ~u : (u | 0x80000000u);
}
__device__ __forceinline__ float decf(u32 u) {
    return (u & 0x80000000u) ? __uint_as_float(u ^ 0x80000000u)
                             : __uint_as_float(~u);
}

// ---------------------------------------------------------------- prep ----
// one wave per span row: gather 2x768 fp32 -> bf16, fp32 sum of squares
__global__ __launch_bounds__(256) void prep_kernel(
    const float* __restrict__ tok_support, const float* __restrict__ tok_query,
    const int* __restrict__ start_s, const int* __restrict__ end_s,
    const int* __restrict__ start_q, const int* __restrict__ end_q,
    u16* __restrict__ Qb, u16* __restrict__ Sb,
    float* __restrict__ qn, float* __restrict__ sn) {
    int gw = (blockIdx.x * 256 + threadIdx.x) >> 6;
    int lane = threadIdx.x & 63;
    const float* tok;
    const int *st, *en;
    u16* dst;
    float* nrm;
    int r;
    if (gw < NQ) {
        r = gw; tok = tok_query; st = start_q; en = end_q;
        dst = Qb + (size_t)r * KDIM; nrm = qn + r;
    } else {
        r = gw - NQ; tok = tok_support; st = start_s; en = end_s;
        dst = Sb + (size_t)r * KDIM; nrm = sn + r;
    }
    float ssum = 0.0f;
#pragma unroll
    for (int h = 0; h < 2; ++h) {
        const float4* src4 =
            (const float4*)(tok + (size_t)(h ? en[r] : st[r]) * D_TOK);
        u16* d = dst + h * D_TOK;
#pragma unroll
        for (int it = 0; it < 3; ++it) {
            int i = lane + it * 64;
            float4 v = src4[i];
            ssum += v.x * v.x + v.y * v.y + v.z * v.z + v.w * v.w;
            ushort4 b;
            b.x = f2bf(v.x); b.y = f2bf(v.y); b.z = f2bf(v.z); b.w = f2bf(v.w);
            ((ushort4*)d)[i] = b;
        }
    }
#pragma unroll
    for (int s = 32; s; s >>= 1) ssum += __shfl_xor(ssum, s);
    if (lane == 0) *nrm = ssum;
}

// ---------------------------------------------------------------- init ----
__global__ void init_enc_kernel(u32* __restrict__ enc) {
    int i = blockIdx.x * 256 + threadIdx.x;
    if (i < NQ * NL) enc[i] = 0x00800000u;  // enc(-FLT_MAX)
}

// ---------------------------------------------------------------- gemm ----
// 128x128 tile, BK=32, 4 waves (2x2), 16x16x32 bf16 MFMA, fused label-max
__global__ __launch_bounds__(256) void gemm_kernel(
    const u16* __restrict__ Qb, const u16* __restrict__ Sb,
    const float* __restrict__ qn, const float* __restrict__ sn,
    const int* __restrict__ labels, u32* __restrict__ enc) {
    __shared__ u16 As[128 * 32];
    __shared__ u16 Bs[128 * 32];
    const int tid = threadIdx.x;
    const int lane = tid & 63;
    const int wid = tid >> 6;
    const int wm = wid >> 1;  // 0..1
    const int wn = wid & 1;   // 0..1
    const int l15 = lane & 15;
    const int lq = lane >> 4;
    const int bm = blockIdx.y * 128;
    const int bn = blockIdx.x * 128;

    f32x4 acc[4][4] = {};

    const int srow = tid >> 2;       // 0..63
    const int scol = (tid & 3) * 8;  // k elem offset
    u16* gA = (u16*)(Qb + (size_t)(bm + srow) * KDIM + scol);
    u16* gB = (u16*)(Sb + (size_t)(bn + srow) * KDIM + scol);
    u16* lA = As + tid * 8;  // byte offset tid*16 — linear per wave
    u16* lB = Bs + tid * 8;

    for (int k0 = 0; k0 < KDIM; k0 += 32) {
        __syncthreads();
        __builtin_amdgcn_global_load_lds(
            (__attribute__((address_space(1))) void*)(gA + k0),
            (__attribute__((address_space(3))) void*)lA, 16, 0, 0);
        __builtin_amdgcn_global_load_lds(
            (__attribute__((address_space(1))) void*)(gA + 64 * KDIM + k0),
            (__attribute__((address_space(3))) void*)(lA + 2048), 16, 0, 0);
        __builtin_amdgcn_global_load_lds(
            (__attribute__((address_space(1))) void*)(gB + k0),
            (__attribute__((address_space(3))) void*)lB, 16, 0, 0);
        __builtin_amdgcn_global_load_lds(
            (__attribute__((address_space(1))) void*)(gB + 64 * KDIM + k0),
            (__attribute__((address_space(3))) void*)(lB + 2048), 16, 0, 0);
        __syncthreads();
        bf16x8 af[4], bfr[4];
#pragma unroll
        for (int m = 0; m < 4; ++m)
            af[m] = *(const bf16x8*)(As + (wm * 64 + m * 16 + l15) * 32 + lq * 8);
#pragma unroll
        for (int n = 0; n < 4; ++n)
            bfr[n] = *(const bf16x8*)(Bs + (wn * 64 + n * 16 + l15) * 32 + lq * 8);
#pragma unroll
        for (int m = 0; m < 4; ++m)
#pragma unroll
            for (int n = 0; n < 4; ++n)
                acc[m][n] = __builtin_amdgcn_mfma_f32_16x16x32_bf16(
                    af[m], bfr[n], acc[m][n], 0, 0, 0);
    }

    // ---- fused epilogue: dist = 2*acc - qn - sn; per-label max ----
    float sncol[4];
    int lab[4];
#pragma unroll
    for (int n = 0; n < 4; ++n) {
        int c = bn + wn * 64 + n * 16 + l15;
        sncol[n] = sn[c];
        lab[n] = labels[c];
    }
    const float NEGF = -3.402823466e38f;
#pragma unroll
    for (int m = 0; m < 4; ++m) {
#pragma unroll
        for (int j = 0; j < 4; ++j) {
            int row = bm + wm * 64 + m * 16 + lq * 4 + j;
            float q2 = qn[row];
            float lmax[NL];
#pragma unroll
            for (int t = 0; t < NL; ++t) lmax[t] = NEGF;
#pragma unroll
            for (int n = 0; n < 4; ++n) {
                float v = 2.0f * acc[m][n][j] - q2 - sncol[n];
#pragma unroll
                for (int t = 0; t < NL; ++t)
                    lmax[t] = fmaxf(lmax[t], lab[n] == t ? v : NEGF);
            }
            // reduce across the 16 lanes (cols) of this quadrant
#pragma unroll
            for (int t = 0; t < NL; ++t) {
                float v = lmax[t];
                v = fmaxf(v, __shfl_xor(v, 1));
                v = fmaxf(v, __shfl_xor(v, 2));
                v = fmaxf(v, __shfl_xor(v, 4));
                v = fmaxf(v, __shfl_xor(v, 8));
                lmax[t] = v;
            }
#pragma unroll
            for (int t = 0; t < NL; ++t) {
                if (l15 == t) atomicMax(&enc[row * NL + t], encf(lmax[t]));
            }
        }
    }
}

// --------------------------------------------------------------- final ----
__global__ void final_kernel(const u32* __restrict__ enc,
                             float* __restrict__ out) {
    int q = blockIdx.x * 256 + threadIdx.x;
    if (q >= NQ) return;
    float best = -3.402823466e38f;
    int bi = 0;
#pragma unroll
    for (int t = 0; t < NL; ++t) {
        float v = decf(enc[q * NL + t]);
        out[q * NL + t] = v;
        if (v > best) { best = v; bi = t; }  // first max wins (argmax semantics)
    }
    out[NQ * NL + q] = (float)bi;
}

// -------------------------------------------------------------- launch ----
extern "C" void kernel_launch(void* const* d_in, const int* in_sizes, int n_in,
                              void* d_out, int out_size, void* d_ws,
                              size_t ws_size, hipStream_t stream) {
    const float* tok_support = (const float*)d_in[0];
    const float* tok_query = (const float*)d_in[1];
    const int* start_s = (const int*)d_in[2];
    const int* end_s = (const int*)d_in[3];
    const int* start_q = (const int*)d_in[4];
    const int* end_q = (const int*)d_in[5];
    const int* labels_s = (const int*)d_in[6];

    char* ws = (char*)d_ws;
    u16* Qb = (u16*)ws;                   // 8192*1536*2 = 25165824 B
    u16* Sb = (u16*)(ws + 25165824);      // 25165824 B
    float* qn = (float*)(ws + 50331648);  // 32768 B
    float* sn = (float*)(ws + 50364416);  // 32768 B
    u32* enc = (u32*)(ws + 50397184);     // 196608 B

    prep_kernel<<<dim3((NQ + NS) / 4), dim3(256), 0, stream>>>(
        tok_support, tok_query, start_s, end_s, start_q, end_q, Qb, Sb, qn, sn);
    init_enc_kernel<<<dim3((NQ * NL + 255) / 256), dim3(256), 0, stream>>>(enc);
    gemm_kernel<<<dim3(64, 64), dim3(256), 0, stream>>>(Qb, Sb, qn, sn,
                                                        labels_s, enc);
    final_kernel<<<dim3(NQ / 256), dim3(256), 0, stream>>>(enc, (float*)d_out);
}

// Round 2
// 567.023 us; speedup vs baseline: 1.3464x; 1.3464x over previous
//
#include <hip/hip_runtime.h>

#define D_TOK 768
#define NS 8192
#define NQ 8192
#define NL 6
#define KDIM 1536
#define NTN 64  // N tiles (128 each)
#define NT_K 48 // K steps of 32

typedef __attribute__((ext_vector_type(4))) float f32x4;
typedef __attribute__((ext_vector_type(8))) short bf16x8;
typedef unsigned int u32;
typedef unsigned short u16;

__device__ __forceinline__ u16 f2bf(float f) {
    u32 u = __float_as_uint(f);
    u32 r = (u + 0x7FFFu + ((u >> 16) & 1u)) >> 16;  // RNE
    return (u16)r;
}

// ---------------------------------------------------------------- prep ----
// one wave per span row: gather 2x768 fp32 -> bf16, fp32 sum of squares
__global__ __launch_bounds__(256) void prep_kernel(
    const float* __restrict__ tok_support, const float* __restrict__ tok_query,
    const int* __restrict__ start_s, const int* __restrict__ end_s,
    const int* __restrict__ start_q, const int* __restrict__ end_q,
    u16* __restrict__ Qb, u16* __restrict__ Sb,
    float* __restrict__ qn, float* __restrict__ sn) {
    int gw = (blockIdx.x * 256 + threadIdx.x) >> 6;
    int lane = threadIdx.x & 63;
    const float* tok;
    const int *st, *en;
    u16* dst;
    float* nrm;
    int r;
    if (gw < NQ) {
        r = gw; tok = tok_query; st = start_q; en = end_q;
        dst = Qb + (size_t)r * KDIM; nrm = qn + r;
    } else {
        r = gw - NQ; tok = tok_support; st = start_s; en = end_s;
        dst = Sb + (size_t)r * KDIM; nrm = sn + r;
    }
    float ssum = 0.0f;
#pragma unroll
    for (int h = 0; h < 2; ++h) {
        const float4* src4 =
            (const float4*)(tok + (size_t)(h ? en[r] : st[r]) * D_TOK);
        u16* d = dst + h * D_TOK;
#pragma unroll
        for (int it = 0; it < 3; ++it) {
            int i = lane + it * 64;
            float4 v = src4[i];
            ssum += v.x * v.x + v.y * v.y + v.z * v.z + v.w * v.w;
            ushort4 b;
            b.x = f2bf(v.x); b.y = f2bf(v.y); b.z = f2bf(v.z); b.w = f2bf(v.w);
            ((ushort4*)d)[i] = b;
        }
    }
#pragma unroll
    for (int s = 32; s; s >>= 1) ssum += __shfl_xor(ssum, s);
    if (lane == 0) *nrm = ssum;
}

// ---------------------------------------------------------------- gemm ----
// 128x128 tile, BK=32, 4 waves (2x2), 2-phase double-buffered staging,
// fused label-max epilogue -> per-block partials (plain stores, no atomics)
__global__ __launch_bounds__(256) void gemm_kernel(
    const u16* __restrict__ Qb, const u16* __restrict__ Sb,
    const float* __restrict__ qn, const float* __restrict__ sn,
    const int* __restrict__ labels, float* __restrict__ part) {
    __shared__ u16 As[2][128 * 32];
    __shared__ u16 Bs[2][128 * 32];
    __shared__ float red[2][128][NL];

    const int tid = threadIdx.x;
    const int lane = tid & 63;
    const int wid = tid >> 6;
    const int wm = wid >> 1;  // 0..1
    const int wn = wid & 1;   // 0..1
    const int l15 = lane & 15;
    const int lq = lane >> 4;

    // XCD-aware swizzle (bijective): xcd gets a supertile-row; 8x8 supertiles
    const int bid = blockIdx.x;
    const int x = bid & 7;       // xcd
    const int lid = bid >> 3;    // 0..511
    const int stn = lid >> 6;    // 0..7
    const int inner = lid & 63;  // 0..63
    const int tm = x * 8 + (inner >> 3);
    const int tn = stn * 8 + (inner & 7);
    const int bm = tm * 128;
    const int bn = tn * 128;

    f32x4 acc[4][4] = {};

    const int srow = tid >> 2;       // 0..63
    const int scol = (tid & 3) * 8;  // k elem offset
    const u16* gA = Qb + (size_t)(bm + srow) * KDIM + scol;
    const u16* gB = Sb + (size_t)(bn + srow) * KDIM + scol;

#define STAGE(buf, k0)                                                        \
    do {                                                                      \
        __builtin_amdgcn_global_load_lds(                                     \
            (__attribute__((address_space(1))) void*)(u16*)(gA + (k0)),       \
            (__attribute__((address_space(3))) void*)(As[buf] + tid * 8), 16, \
            0, 0);                                                            \
        __builtin_amdgcn_global_load_lds(                                     \
            (__attribute__((address_space(1))) void*)(u16*)(gA + 64 * KDIM +  \
                                                            (k0)),            \
            (__attribute__((address_space(3))) void*)(As[buf] + 2048 +        \
                                                      tid * 8),               \
            16, 0, 0);                                                        \
        __builtin_amdgcn_global_load_lds(                                     \
            (__attribute__((address_space(1))) void*)(u16*)(gB + (k0)),       \
            (__attribute__((address_space(3))) void*)(Bs[buf] + tid * 8), 16, \
            0, 0);                                                            \
        __builtin_amdgcn_global_load_lds(                                     \
            (__attribute__((address_space(1))) void*)(u16*)(gB + 64 * KDIM +  \
                                                            (k0)),            \
            (__attribute__((address_space(3))) void*)(Bs[buf] + 2048 +        \
                                                      tid * 8),               \
            16, 0, 0);                                                        \
    } while (0)

    STAGE(0, 0);
    __syncthreads();  // vmcnt(0) drained by compiler before barrier
    int cur = 0;
    for (int t = 0; t < NT_K; ++t) {
        if (t + 1 < NT_K) STAGE(cur ^ 1, (t + 1) * 32);  // prefetch next tile
        bf16x8 af[4], bfr[4];
#pragma unroll
        for (int m = 0; m < 4; ++m)
            af[m] = *(const bf16x8*)(As[cur] + (wm * 64 + m * 16 + l15) * 32 +
                                     lq * 8);
#pragma unroll
        for (int n = 0; n < 4; ++n)
            bfr[n] = *(const bf16x8*)(Bs[cur] + (wn * 64 + n * 16 + l15) * 32 +
                                      lq * 8);
#pragma unroll
        for (int m = 0; m < 4; ++m)
#pragma unroll
            for (int n = 0; n < 4; ++n)
                acc[m][n] = __builtin_amdgcn_mfma_f32_16x16x32_bf16(
                    af[m], bfr[n], acc[m][n], 0, 0, 0);
        __syncthreads();  // drains prefetch vmcnt + lgkm; one barrier/K-step
        cur ^= 1;
    }

    // ---- fused epilogue: dist = 2*acc - qn - sn; per-label max ----
    float sncol[4];
    int lab[4];
#pragma unroll
    for (int n = 0; n < 4; ++n) {
        int c = bn + wn * 64 + n * 16 + l15;
        sncol[n] = sn[c];
        lab[n] = labels[c];
    }
    const float NEGF = -3.402823466e38f;
#pragma unroll
    for (int m = 0; m < 4; ++m) {
#pragma unroll
        for (int j = 0; j < 4; ++j) {
            int rl = wm * 64 + m * 16 + lq * 4 + j;  // local row
            float q2 = qn[bm + rl];
            float lmax[NL];
#pragma unroll
            for (int t = 0; t < NL; ++t) lmax[t] = NEGF;
#pragma unroll
            for (int n = 0; n < 4; ++n) {
                float v = 2.0f * acc[m][n][j] - q2 - sncol[n];
#pragma unroll
                for (int t = 0; t < NL; ++t)
                    lmax[t] = fmaxf(lmax[t], lab[n] == t ? v : NEGF);
            }
            // reduce across the 16 lanes (cols) of this quadrant
#pragma unroll
            for (int t = 0; t < NL; ++t) {
                float v = lmax[t];
                v = fmaxf(v, __shfl_xor(v, 1));
                v = fmaxf(v, __shfl_xor(v, 2));
                v = fmaxf(v, __shfl_xor(v, 4));
                v = fmaxf(v, __shfl_xor(v, 8));
                if (l15 == t) red[wn][rl][t] = v;  // static index (rule #20)
            }
        }
    }
    __syncthreads();
    // merge wn halves and store partials: 128 rows x 6 labels
    for (int i = tid; i < 128 * NL; i += 256) {
        int r = i / NL, t = i - r * NL;
        float v = fmaxf(red[0][r][t], red[1][r][t]);
        part[((size_t)(bm + r) * NTN + tn) * NL + t] = v;
    }
#undef STAGE
}

// --------------------------------------------------------------- final ----
// one wave per query row: lane = n-tile; reduce 64 partials x 6 labels
__global__ __launch_bounds__(256) void final_kernel(
    const float* __restrict__ part, float* __restrict__ out) {
    int q = (blockIdx.x * 256 + threadIdx.x) >> 6;
    int lane = threadIdx.x & 63;
    const float* p = part + ((size_t)q * NTN + lane) * NL;
    float v[NL];
#pragma unroll
    for (int t = 0; t < NL; ++t) v[t] = p[t];
#pragma unroll
    for (int t = 0; t < NL; ++t) {
#pragma unroll
        for (int s = 32; s; s >>= 1) v[t] = fmaxf(v[t], __shfl_xor(v[t], s));
    }
    if (lane == 0) {
        float best = -3.402823466e38f;
        int bi = 0;
#pragma unroll
        for (int t = 0; t < NL; ++t) {
            out[q * NL + t] = v[t];
            if (v[t] > best) { best = v[t]; bi = t; }  // first max wins
        }
        out[NQ * NL + q] = (float)bi;
    }
}

// -------------------------------------------------------------- launch ----
extern "C" void kernel_launch(void* const* d_in, const int* in_sizes, int n_in,
                              void* d_out, int out_size, void* d_ws,
                              size_t ws_size, hipStream_t stream) {
    const float* tok_support = (const float*)d_in[0];
    const float* tok_query = (const float*)d_in[1];
    const int* start_s = (const int*)d_in[2];
    const int* end_s = (const int*)d_in[3];
    const int* start_q = (const int*)d_in[4];
    const int* end_q = (const int*)d_in[5];
    const int* labels_s = (const int*)d_in[6];

    char* ws = (char*)d_ws;
    u16* Qb = (u16*)ws;                    // 25,165,824 B
    u16* Sb = (u16*)(ws + 25165824);       // 25,165,824 B
    float* qn = (float*)(ws + 50331648);   // 32,768 B
    float* sn = (float*)(ws + 50364416);   // 32,768 B
    float* part = (float*)(ws + 50397184); // 8192*64*6*4 = 12,582,912 B

    prep_kernel<<<dim3((NQ + NS) / 4), dim3(256), 0, stream>>>(
        tok_support, tok_query, start_s, end_s, start_q, end_q, Qb, Sb, qn, sn);
    gemm_kernel<<<dim3(64 * 64), dim3(256), 0, stream>>>(Qb, Sb, qn, sn,
                                                         labels_s, part);
    final_kernel<<<dim3(NQ * 64 / 256), dim3(256), 0, stream>>>(part,
                                                                (float*)d_out);
}

// Round 3
// 543.543 us; speedup vs baseline: 1.4045x; 1.0432x over previous
//
#include <hip/hip_runtime.h>

#define D_TOK 768
#define NS 8192
#define NQ 8192
#define NL 6
#define KDIM 1536
#define BM 256
#define BN 256
#define NTN 32   // N tiles of 256
#define NITER 12 // 24 K-tiles of 64, 2 per loop iteration

typedef __attribute__((ext_vector_type(4))) float f32x4;
typedef __attribute__((ext_vector_type(8))) short bf16x8;
typedef unsigned int u32;
typedef unsigned short u16;

__device__ __forceinline__ u16 f2bf(float f) {
    u32 u = __float_as_uint(f);
    u32 r = (u + 0x7FFFu + ((u >> 16) & 1u)) >> 16;  // RNE
    return (u16)r;
}

// ---------------------------------------------------------------- prep ----
__global__ __launch_bounds__(256) void prep_kernel(
    const float* __restrict__ tok_support, const float* __restrict__ tok_query,
    const int* __restrict__ start_s, const int* __restrict__ end_s,
    const int* __restrict__ start_q, const int* __restrict__ end_q,
    u16* __restrict__ Qb, u16* __restrict__ Sb,
    float* __restrict__ qn, float* __restrict__ sn) {
    int gw = (blockIdx.x * 256 + threadIdx.x) >> 6;
    int lane = threadIdx.x & 63;
    const float* tok;
    const int *st, *en;
    u16* dst;
    float* nrm;
    int r;
    if (gw < NQ) {
        r = gw; tok = tok_query; st = start_q; en = end_q;
        dst = Qb + (size_t)r * KDIM; nrm = qn + r;
    } else {
        r = gw - NQ; tok = tok_support; st = start_s; en = end_s;
        dst = Sb + (size_t)r * KDIM; nrm = sn + r;
    }
    float ssum = 0.0f;
#pragma unroll
    for (int h = 0; h < 2; ++h) {
        const float4* src4 =
            (const float4*)(tok + (size_t)(h ? en[r] : st[r]) * D_TOK);
        u16* d = dst + h * D_TOK;
#pragma unroll
        for (int it = 0; it < 3; ++it) {
            int i = lane + it * 64;
            float4 v = src4[i];
            ssum += v.x * v.x + v.y * v.y + v.z * v.z + v.w * v.w;
            ushort4 b;
            b.x = f2bf(v.x); b.y = f2bf(v.y); b.z = f2bf(v.z); b.w = f2bf(v.w);
            ((ushort4*)d)[i] = b;
        }
    }
#pragma unroll
    for (int s = 32; s; s >>= 1) ssum += __shfl_xor(ssum, s);
    if (lane == 0) *nrm = ssum;
}

// ---------------------------------------------------------------- gemm ----
// 256x256 tile, BK=64, 8 waves (2Mx4N), 8-phase schedule, st_16x32 LDS
// swizzle (inverse-swizzled gload_lds source + swizzled ds_read), counted
// vmcnt at phases 4/8, setprio around MFMA clusters. Fused label-max.
__global__ __launch_bounds__(512) void gemm_kernel(
    const u16* __restrict__ Qb, const u16* __restrict__ Sb,
    const float* __restrict__ qn, const float* __restrict__ sn,
    const int* __restrict__ labels, float* __restrict__ part) {
    __shared__ char lds[131072];
    u16* As = (u16*)lds;             // 2 bufs x 32768 B
    u16* Bs = (u16*)(lds + 65536);   // 2 bufs x 32768 B
    const char* Ab = (const char*)lds;
    const char* Bb = (const char*)(lds + 65536);

    const int tid = threadIdx.x;
    const int lane = tid & 63;
    const int wid = tid >> 6;
    const int wm = wid >> 2;  // 0..1
    const int wn = wid & 3;   // 0..3
    const int l15 = lane & 15;
    const int lq = lane >> 4;

    // XCD swizzle: 1024 blocks, 128/XCD; per XCD a 4(tm) x 32(tn) panel
    const int bid = blockIdx.x;
    const int x = bid & 7;
    const int lid = bid >> 3;       // 0..127
    const int tm = x * 4 + (lid & 3);
    const int tn = lid >> 2;        // 0..31
    const int bm = tm * BM;
    const int bn = tn * BN;

    // staging source precompute: physical LDS byte p -> logical (row,col)
    int grow[4], gcol[4];
#pragma unroll
    for (int j = 0; j < 4; ++j) {
        int p = j * 8192 + tid * 16;
        int q = p ^ (((p >> 9) & 1) << 5);
        grow[j] = q >> 7;          // 0..255
        gcol[j] = (q & 127) >> 1;  // 0..63 (bf16 elems)
    }
    const u16* gA = Qb + (size_t)bm * KDIM;
    const u16* gB = Sb + (size_t)bn * KDIM;

    // swizzled ds_read bases (byte offsets within one 32 KiB tile buffer)
    const int swz = ((l15 >> 2) & 1) << 5;
    const int aBase = ((wm * 128 + l15) * 128 + lq * 16) ^ swz;
    const int bBase = ((wn * 64 + l15) * 128 + lq * 16) ^ swz;

    f32x4 acc[8][4] = {};
    bf16x8 af[4][2], bf[2][2];

#define STG(dst, g, b, t)                                                     \
    do {                                                                      \
        _Pragma("unroll") for (int j = 0; j < 4; ++j) {                       \
            __builtin_amdgcn_global_load_lds(                                 \
                (__attribute__((address_space(1))) void*)(u16*)(              \
                    (g) + (size_t)grow[j] * KDIM + (t) * 64 + gcol[j]),       \
                (__attribute__((address_space(3))) void*)(                    \
                    (dst) + (b) * 16384 + j * 4096 + tid * 8),                \
                16, 0, 0);                                                    \
        }                                                                     \
    } while (0)

#define READ_A(b, m0)                                                         \
    do {                                                                      \
        _Pragma("unroll") for (int i = 0; i < 4; ++i)                         \
            _Pragma("unroll") for (int kk = 0; kk < 2; ++kk)                  \
                af[i][kk] = *(const bf16x8*)(Ab + (b) * 32768 + aBase +       \
                                             ((m0) + i) * 2048 + kk * 64);    \
    } while (0)

#define READ_B(b, n0)                                                         \
    do {                                                                      \
        _Pragma("unroll") for (int jj = 0; jj < 2; ++jj)                      \
            _Pragma("unroll") for (int kk = 0; kk < 2; ++kk)                  \
                bf[jj][kk] = *(const bf16x8*)(Bb + (b) * 32768 + bBase +      \
                                              ((n0) + jj) * 2048 + kk * 64);  \
    } while (0)

#define MFMA_Q(m0, n0)                                                        \
    do {                                                                      \
        __builtin_amdgcn_s_setprio(1);                                        \
        _Pragma("unroll") for (int i = 0; i < 4; ++i)                         \
            _Pragma("unroll") for (int jj = 0; jj < 2; ++jj)                  \
                _Pragma("unroll") for (int kk = 0; kk < 2; ++kk)              \
                    acc[(m0) + i][(n0) + jj] =                                \
                        __builtin_amdgcn_mfma_f32_16x16x32_bf16(              \
                            af[i][kk], bf[jj][kk], acc[(m0) + i][(n0) + jj],  \
                            0, 0, 0);                                         \
        __builtin_amdgcn_s_setprio(0);                                        \
    } while (0)

#define BAR __builtin_amdgcn_s_barrier()
#define HANDOFF(N)                                                            \
    do {                                                                      \
        __builtin_amdgcn_sched_barrier(0);                                    \
        asm volatile("s_waitcnt vmcnt(" #N ")" ::: "memory");                 \
        __builtin_amdgcn_s_barrier();                                         \
        __builtin_amdgcn_sched_barrier(0);                                    \
    } while (0)

    // prologue: tile0 (A+B) -> buf0, tile1 A -> buf1; need tile0 landed
    STG(As, gA, 0, 0);
    STG(Bs, gB, 0, 0);
    STG(As, gA, 1, 1);
    HANDOFF(4);

#pragma unroll 1
    for (int it = 0; it < NITER; ++it) {
        const int more = (it < NITER - 1);
        // ph1: buf0 A(m0-3)+B(n0-1); stage B(tile 2it+1) -> buf1
        READ_A(0, 0);
        READ_B(0, 0);
        STG(Bs, gB, 1, 2 * it + 1);
        BAR;
        MFMA_Q(0, 0);
        BAR;
        // ph2: buf0 B(n2-3)
        READ_B(0, 2);
        BAR;
        MFMA_Q(0, 2);
        BAR;
        // ph3: buf0 A(m4-7)+B(n0-1)
        READ_A(0, 4);
        READ_B(0, 0);
        BAR;
        MFMA_Q(4, 0);
        BAR;
        // ph4: buf0 B(n2-3); stage A(tile 2it+2) -> buf0; handoff (buf1 ready)
        READ_B(0, 2);
        if (more) STG(As, gA, 0, 2 * it + 2);
        BAR;
        MFMA_Q(4, 2);
        if (more) { HANDOFF(4); } else { HANDOFF(0); }
        // ph5: buf1 A(m0-3)+B(n0-1); stage B(tile 2it+2) -> buf0
        READ_A(1, 0);
        READ_B(1, 0);
        if (more) STG(Bs, gB, 0, 2 * it + 2);
        BAR;
        MFMA_Q(0, 0);
        BAR;
        // ph6: buf1 B(n2-3)
        READ_B(1, 2);
        BAR;
        MFMA_Q(0, 2);
        BAR;
        // ph7: buf1 A(m4-7)+B(n0-1)
        READ_A(1, 4);
        READ_B(1, 0);
        BAR;
        MFMA_Q(4, 0);
        BAR;
        // ph8: buf1 B(n2-3); stage A(tile 2it+3) -> buf1; handoff (buf0 ready)
        READ_B(1, 2);
        if (more) STG(As, gA, 1, 2 * it + 3);
        BAR;
        MFMA_Q(4, 2);
        if (more) { HANDOFF(4); } else { HANDOFF(0); }
    }

    // ---- fused epilogue: dist = 2*acc - qn - sn; per-label max ----
    float* red = (float*)lds;  // [256 rows][4 wn][NL] = 24576 B (reuse)
    const float NEGF = -3.402823466e38f;
    float sncol[4];
    int lab[4];
#pragma unroll
    for (int n = 0; n < 4; ++n) {
        int c = bn + wn * 64 + n * 16 + l15;
        sncol[n] = sn[c];
        lab[n] = labels[c];
    }
#pragma unroll
    for (int m = 0; m < 8; ++m) {
#pragma unroll
        for (int j = 0; j < 4; ++j) {
            int rl = m * 16 + lq * 4 + j;  // 0..127 within this wm half
            float q2 = qn[bm + wm * 128 + rl];
            float lmax[NL];
#pragma unroll
            for (int t = 0; t < NL; ++t) lmax[t] = NEGF;
#pragma unroll
            for (int n = 0; n < 4; ++n) {
                float v = 2.0f * acc[m][n][j] - q2 - sncol[n];
#pragma unroll
                for (int t = 0; t < NL; ++t)
                    lmax[t] = fmaxf(lmax[t], lab[n] == t ? v : NEGF);
            }
#pragma unroll
            for (int t = 0; t < NL; ++t) {
                float v = lmax[t];
                v = fmaxf(v, __shfl_xor(v, 1));
                v = fmaxf(v, __shfl_xor(v, 2));
                v = fmaxf(v, __shfl_xor(v, 4));
                v = fmaxf(v, __shfl_xor(v, 8));
                if (l15 == t)
                    red[((wm * 128 + rl) * 4 + wn) * NL + t] = v;
            }
        }
    }
    __syncthreads();
    for (int i = tid; i < 256 * NL; i += 512) {
        int rf = i / NL, t = i - rf * NL;
        float v = fmaxf(
            fmaxf(red[(rf * 4 + 0) * NL + t], red[(rf * 4 + 1) * NL + t]),
            fmaxf(red[(rf * 4 + 2) * NL + t], red[(rf * 4 + 3) * NL + t]));
        part[(size_t)(bm + rf) * (NTN * NL) + tn * NL + t] = v;
    }
#undef STG
#undef READ_A
#undef READ_B
#undef MFMA_Q
#undef BAR
#undef HANDOFF
}

// --------------------------------------------------------------- final ----
__global__ __launch_bounds__(256) void final_kernel(
    const float* __restrict__ part, float* __restrict__ out) {
    int q = (blockIdx.x * 256 + threadIdx.x) >> 6;
    int lane = threadIdx.x & 63;
    const float NEGF = -3.402823466e38f;
    float v[NL];
    if (lane < NTN) {
        const float* p = part + ((size_t)q * NTN + lane) * NL;
#pragma unroll
        for (int t = 0; t < NL; ++t) v[t] = p[t];
    } else {
#pragma unroll
        for (int t = 0; t < NL; ++t) v[t] = NEGF;
    }
#pragma unroll
    for (int t = 0; t < NL; ++t) {
#pragma unroll
        for (int s = 32; s; s >>= 1) v[t] = fmaxf(v[t], __shfl_xor(v[t], s));
    }
    if (lane == 0) {
        float best = NEGF;
        int bi = 0;
#pragma unroll
        for (int t = 0; t < NL; ++t) {
            out[q * NL + t] = v[t];
            if (v[t] > best) { best = v[t]; bi = t; }  // first max wins
        }
        out[NQ * NL + q] = (float)bi;
    }
}

// -------------------------------------------------------------- launch ----
extern "C" void kernel_launch(void* const* d_in, const int* in_sizes, int n_in,
                              void* d_out, int out_size, void* d_ws,
                              size_t ws_size, hipStream_t stream) {
    const float* tok_support = (const float*)d_in[0];
    const float* tok_query = (const float*)d_in[1];
    const int* start_s = (const int*)d_in[2];
    const int* end_s = (const int*)d_in[3];
    const int* start_q = (const int*)d_in[4];
    const int* end_q = (const int*)d_in[5];
    const int* labels_s = (const int*)d_in[6];

    char* ws = (char*)d_ws;
    u16* Qb = (u16*)ws;                     // 25,165,824 B
    u16* Sb = (u16*)(ws + 25165824);        // 25,165,824 B
    float* qn = (float*)(ws + 50331648);    // 32,768 B
    float* sn = (float*)(ws + 50364416);    // 32,768 B
    float* part = (float*)(ws + 50397184);  // 8192*32*6*4 = 6,291,456 B

    prep_kernel<<<dim3((NQ + NS) / 4), dim3(256), 0, stream>>>(
        tok_support, tok_query, start_s, end_s, start_q, end_q, Qb, Sb, qn, sn);
    gemm_kernel<<<dim3(32 * 32), dim3(512), 0, stream>>>(Qb, Sb, qn, sn,
                                                         labels_s, part);
    final_kernel<<<dim3(NQ * 64 / 256), dim3(256), 0, stream>>>(part,
                                                                (float*)d_out);
}

// Round 6
// 512.343 us; speedup vs baseline: 1.4900x; 1.0609x over previous
//
#include <hip/hip_runtime.h>

#define D_TOK 768
#define NS 8192
#define NQ 8192
#define NL 6
#define KDIM 1536
#define BM 256
#define BN 256
#define NTN 32   // N tiles of 256
#define NITER 12 // 24 K-tiles of 64, 2 per loop iteration

typedef __attribute__((ext_vector_type(4))) float f32x4;
typedef __attribute__((ext_vector_type(8))) short bf16x8;
typedef unsigned int u32;
typedef unsigned short u16;

__device__ __forceinline__ u16 f2bf(float f) {
    u32 u = __float_as_uint(f);
    u32 r = (u + 0x7FFFu + ((u >> 16) & 1u)) >> 16;  // RNE
    return (u16)r;
}

// ---------------------------------------------------------------- prep ----
__global__ __launch_bounds__(256) void prep_kernel(
    const float* __restrict__ tok_support, const float* __restrict__ tok_query,
    const int* __restrict__ start_s, const int* __restrict__ end_s,
    const int* __restrict__ start_q, const int* __restrict__ end_q,
    u16* __restrict__ Qb, u16* __restrict__ Sb,
    float* __restrict__ qn, float* __restrict__ sn) {
    int gw = (blockIdx.x * 256 + threadIdx.x) >> 6;
    int lane = threadIdx.x & 63;
    const float* tok;
    const int *st, *en;
    u16* dst;
    float* nrm;
    int r;
    if (gw < NQ) {
        r = gw; tok = tok_query; st = start_q; en = end_q;
        dst = Qb + (size_t)r * KDIM; nrm = qn + r;
    } else {
        r = gw - NQ; tok = tok_support; st = start_s; en = end_s;
        dst = Sb + (size_t)r * KDIM; nrm = sn + r;
    }
    float ssum = 0.0f;
#pragma unroll
    for (int h = 0; h < 2; ++h) {
        const float4* src4 =
            (const float4*)(tok + (size_t)(h ? en[r] : st[r]) * D_TOK);
        u16* d = dst + h * D_TOK;
#pragma unroll
        for (int it = 0; it < 3; ++it) {
            int i = lane + it * 64;
            float4 v = src4[i];
            ssum += v.x * v.x + v.y * v.y + v.z * v.z + v.w * v.w;
            ushort4 b;
            b.x = f2bf(v.x); b.y = f2bf(v.y); b.z = f2bf(v.z); b.w = f2bf(v.w);
            ((ushort4*)d)[i] = b;
        }
    }
#pragma unroll
    for (int s = 32; s; s >>= 1) ssum += __shfl_xor(ssum, s);
    if (lane == 0) *nrm = ssum;
}

// ---------------------------------------------------------------- gemm ----
// 256x256, BK=64, 8 waves (2Mx4N). LDS tile [256 rows][64 bf16] with 16B-chunk
// swizzle: phys_chunk = log_chunk ^ (row&7) -> conflict-free ds_read_b128.
// 8 phases per 2 K-tiles; B-frags held in regs for the whole K-tile (24
// b128/K-tile/wave = minimum); counted vmcnt(4) handoffs; setprio on MFMA.
__global__ __launch_bounds__(512) void gemm_kernel(
    const u16* __restrict__ Qb, const u16* __restrict__ Sb,
    const float* __restrict__ qn, const float* __restrict__ sn,
    const int* __restrict__ labels, float* __restrict__ part) {
    __shared__ char lds[131072];
    u16* As = (u16*)lds;                  // 2 bufs x 32768 B
    u16* Bs = (u16*)(lds + 65536);        // 2 bufs x 32768 B
    const char* Ab = (const char*)lds;
    const char* Bb = (const char*)(lds + 65536);

    const int tid = threadIdx.x;
    const int lane = tid & 63;
    const int wid = tid >> 6;
    const int wm = wid >> 2;  // 0..1
    const int wn = wid & 3;   // 0..3
    const int l15 = lane & 15;
    const int lq = lane >> 4;

    // XCD mapping: each XCD owns a 4-wide tn quad (B panels L2-resident)
    const int bid = blockIdx.x;
    const int x = bid & 7;
    const int lid = bid >> 3;           // 0..127
    const int tn = x * 4 + (lid >> 5);  // 0..31
    const int tm = lid & 31;            // 0..31
    const int bm = tm * BM;
    const int bn = tn * BN;

    // staging: linear LDS dest (tid*16B), inverse-swizzled global source
    const int growb = tid >> 3;                      // row within 64-row slab
    const int gcol = ((tid & 7) ^ (growb & 7)) * 8;  // pre-swizzled col (elems)
    const u16* gA = Qb + (size_t)bm * KDIM;
    const u16* gB = Sb + (size_t)bn * KDIM;

    // swizzled ds_read offsets: chunk (lq + 4*kk) ^ (row&7), row&7 == l15&7
    const int xr = l15 & 7;
    const int oK0 = (lq ^ xr) * 16;
    const int oK1 = ((lq + 4) ^ xr) * 16;
    const int aRow = (wm * 128 + l15) * 128;  // byte offset of A row
    const int bRow = (wn * 64 + l15) * 128;   // byte offset of B row

    f32x4 acc[8][4] = {};
    bf16x8 af[2][2], bfr[4][2];

#define STG2(dstU16, g, bsel, j0_, t)                                         \
    do {                                                                      \
        _Pragma("unroll") for (int j = (j0_); j < (j0_) + 2; ++j) {           \
            __builtin_amdgcn_global_load_lds(                                 \
                (__attribute__((address_space(1))) void*)(u16*)(              \
                    (g) + (size_t)(j * 64 + growb) * KDIM +                   \
                    (size_t)(t) * 64 + gcol),                                 \
                (__attribute__((address_space(3))) void*)(                    \
                    (dstU16) + (bsel) * 16384 + j * 4096 + tid * 8),          \
                16, 0, 0);                                                    \
        }                                                                     \
    } while (0)

#define READ_A2(bsel, m0)                                                     \
    do {                                                                      \
        _Pragma("unroll") for (int i = 0; i < 2; ++i)                         \
            _Pragma("unroll") for (int kk = 0; kk < 2; ++kk)                  \
                af[i][kk] = *(const bf16x8*)(Ab + (bsel) * 32768 + aRow +     \
                                             ((m0) + i) * 2048 +              \
                                             (kk ? oK1 : oK0));               \
    } while (0)

#define READ_BALL(bsel)                                                       \
    do {                                                                      \
        _Pragma("unroll") for (int n = 0; n < 4; ++n)                         \
            _Pragma("unroll") for (int kk = 0; kk < 2; ++kk)                  \
                bfr[n][kk] = *(const bf16x8*)(Bb + (bsel) * 32768 + bRow +    \
                                              n * 2048 + (kk ? oK1 : oK0));   \
    } while (0)

#define MFMA_P(m0)                                                            \
    do {                                                                      \
        __builtin_amdgcn_sched_barrier(0);                                    \
        __builtin_amdgcn_s_setprio(1);                                        \
        _Pragma("unroll") for (int i = 0; i < 2; ++i)                         \
            _Pragma("unroll") for (int n = 0; n < 4; ++n)                     \
                _Pragma("unroll") for (int kk = 0; kk < 2; ++kk)              \
                    acc[(m0) + i][n] =                                        \
                        __builtin_amdgcn_mfma_f32_16x16x32_bf16(              \
                            af[i][kk], bfr[n][kk], acc[(m0) + i][n], 0, 0,    \
                            0);                                               \
        __builtin_amdgcn_s_setprio(0);                                        \
    } while (0)

#define BAR __builtin_amdgcn_s_barrier()
#define HANDOFF(N)                                                            \
    do {                                                                      \
        __builtin_amdgcn_sched_barrier(0);                                    \
        asm volatile("s_waitcnt vmcnt(" #N ")" ::: "memory");                 \
        __builtin_amdgcn_s_barrier();                                         \
        __builtin_amdgcn_sched_barrier(0);                                    \
    } while (0)

    // prologue: tile0 A+B -> buf0, tile1 B -> buf1 (12 loads, wait oldest 8)
    STG2(As, gA, 0, 0, 0); STG2(As, gA, 0, 2, 0);
    STG2(Bs, gB, 0, 0, 0); STG2(Bs, gB, 0, 2, 0);
    STG2(Bs, gB, 1, 0, 1); STG2(Bs, gB, 1, 2, 1);
    HANDOFF(4);

#pragma unroll 1
    for (int it = 0; it < NITER; ++it) {
        const int more = (it < NITER - 1);
        const int t1 = 2 * it + 1, t2 = 2 * it + 2, t3 = 2 * it + 3;
        // ph1: buf0 B-all + A(m0-1); stage A(t1)->buf1 rows 0-127
        READ_BALL(0); READ_A2(0, 0);
        STG2(As, gA, 1, 0, t1);
        BAR; MFMA_P(0); BAR;
        // ph2
        READ_A2(0, 2);
        STG2(As, gA, 1, 2, t1);
        BAR; MFMA_P(2); BAR;
        // ph3
        READ_A2(0, 4);
        if (more) STG2(Bs, gB, 0, 0, t2);
        BAR; MFMA_P(4); BAR;
        // ph4: handoff -> buf1 (t1) complete
        READ_A2(0, 6);
        if (more) STG2(Bs, gB, 0, 2, t2);
        BAR; MFMA_P(6);
        if (more) { HANDOFF(4); } else { HANDOFF(0); }
        // ph5: buf1 B-all + A(m0-1); stage A(t2)->buf0
        READ_BALL(1); READ_A2(1, 0);
        if (more) STG2(As, gA, 0, 0, t2);
        BAR; MFMA_P(0); BAR;
        // ph6
        READ_A2(1, 2);
        if (more) STG2(As, gA, 0, 2, t2);
        BAR; MFMA_P(2); BAR;
        // ph7
        READ_A2(1, 4);
        if (more) STG2(Bs, gB, 1, 0, t3);
        BAR; MFMA_P(4); BAR;
        // ph8: handoff -> buf0 (t2) complete
        READ_A2(1, 6);
        if (more) STG2(Bs, gB, 1, 2, t3);
        BAR; MFMA_P(6);
        if (more) { HANDOFF(4); } else { HANDOFF(0); }
    }
    __syncthreads();  // full lgkm/vm drain before LDS reuse

    // ---- fused epilogue: dist = 2*acc - qn - sn; per-label max ----
    float* red = (float*)lds;  // [256 rows][4 wn][NL] = 24576 B (reuse)
    const float NEGF = -3.402823466e38f;
    float sncol[4];
    int lab[4];
#pragma unroll
    for (int n = 0; n < 4; ++n) {
        int c = bn + wn * 64 + n * 16 + l15;
        sncol[n] = sn[c];
        lab[n] = labels[c];
    }
#pragma unroll
    for (int m = 0; m < 8; ++m) {
#pragma unroll
        for (int j = 0; j < 4; ++j) {
            int rl = m * 16 + lq * 4 + j;  // 0..127 within this wm half
            float q2 = qn[bm + wm * 128 + rl];
            float lmax[NL];
#pragma unroll
            for (int t = 0; t < NL; ++t) lmax[t] = NEGF;
#pragma unroll
            for (int n = 0; n < 4; ++n) {
                float v = 2.0f * acc[m][n][j] - q2 - sncol[n];
#pragma unroll
                for (int t = 0; t < NL; ++t)
                    lmax[t] = fmaxf(lmax[t], lab[n] == t ? v : NEGF);
            }
#pragma unroll
            for (int t = 0; t < NL; ++t) {
                float v = lmax[t];
                v = fmaxf(v, __shfl_xor(v, 1));
                v = fmaxf(v, __shfl_xor(v, 2));
                v = fmaxf(v, __shfl_xor(v, 4));
                v = fmaxf(v, __shfl_xor(v, 8));
                if (l15 == t)
                    red[((wm * 128 + rl) * 4 + wn) * NL + t] = v;
            }
        }
    }
    __syncthreads();
    for (int i = tid; i < 256 * NL; i += 512) {
        int rf = i / NL, t = i - rf * NL;
        float v = fmaxf(
            fmaxf(red[(rf * 4 + 0) * NL + t], red[(rf * 4 + 1) * NL + t]),
            fmaxf(red[(rf * 4 + 2) * NL + t], red[(rf * 4 + 3) * NL + t]));
        part[(size_t)(bm + rf) * (NTN * NL) + tn * NL + t] = v;
    }
#undef STG2
#undef READ_A2
#undef READ_BALL
#undef MFMA_P
#undef BAR
#undef HANDOFF
}

// --------------------------------------------------------------- final ----
__global__ __launch_bounds__(256) void final_kernel(
    const float* __restrict__ part, float* __restrict__ out) {
    int q = (blockIdx.x * 256 + threadIdx.x) >> 6;
    int lane = threadIdx.x & 63;
    const float NEGF = -3.402823466e38f;
    float v[NL];
    if (lane < NTN) {
        const float* p = part + ((size_t)q * NTN + lane) * NL;
#pragma unroll
        for (int t = 0; t < NL; ++t) v[t] = p[t];
    } else {
#pragma unroll
        for (int t = 0; t < NL; ++t) v[t] = NEGF;
    }
#pragma unroll
    for (int t = 0; t < NL; ++t) {
#pragma unroll
        for (int s = 32; s; s >>= 1) v[t] = fmaxf(v[t], __shfl_xor(v[t], s));
    }
    if (lane == 0) {
        float best = NEGF;
        int bi = 0;
#pragma unroll
        for (int t = 0; t < NL; ++t) {
            out[q * NL + t] = v[t];
            if (v[t] > best) { best = v[t]; bi = t; }  // first max wins
        }
        out[NQ * NL + q] = (float)bi;
    }
}

// -------------------------------------------------------------- launch ----
extern "C" void kernel_launch(void* const* d_in, const int* in_sizes, int n_in,
                              void* d_out, int out_size, void* d_ws,
                              size_t ws_size, hipStream_t stream) {
    const float* tok_support = (const float*)d_in[0];
    const float* tok_query = (const float*)d_in[1];
    const int* start_s = (const int*)d_in[2];
    const int* end_s = (const int*)d_in[3];
    const int* start_q = (const int*)d_in[4];
    const int* end_q = (const int*)d_in[5];
    const int* labels_s = (const int*)d_in[6];

    char* ws = (char*)d_ws;
    u16* Qb = (u16*)ws;                     // 25,165,824 B
    u16* Sb = (u16*)(ws + 25165824);        // 25,165,824 B
    float* qn = (float*)(ws + 50331648);    // 32,768 B
    float* sn = (float*)(ws + 50364416);    // 32,768 B
    float* part = (float*)(ws + 50397184);  // 8192*32*6*4 = 6,291,456 B

    prep_kernel<<<dim3((NQ + NS) / 4), dim3(256), 0, stream>>>(
        tok_support, tok_query, start_s, end_s, start_q, end_q, Qb, Sb, qn, sn);
    gemm_kernel<<<dim3(32 * 32), dim3(512), 0, stream>>>(Qb, Sb, qn, sn,
                                                         labels_s, part);
    final_kernel<<<dim3(NQ * 64 / 256), dim3(256), 0, stream>>>(part,
                                                                (float*)d_out);
}